// Round 1
// baseline (646.434 us; speedup 1.0000x reference)
//
#include <hip/hip_runtime.h>

#define Bz 64
#define Nn 577
#define Cc 768
#define Hh 12
#define Dd 64
#define SCALE 0.125f

// ws layout (floats):
//   q:      0        .. 49152        [B][C]
//   r:      49152    .. 638976       [B][H][C]   (already * SCALE)
//   logits: 638976   .. 1082112      [B][H][N]
//   attnT:  1082112  .. 1525248      [B][N][H]
//   y:      1525248  .. 2115072      [B][H][C]
//   cls:    2115072  .. 2164224      [B][C]

// ---------------- A: q[b,j] = x[b,0,:] . qkv_w[j,:] + qkv_b[j] ----------------
__global__ __launch_bounds__(768) void k_q(const float* __restrict__ x,
                                           const float* __restrict__ qkv_w,
                                           const float* __restrict__ qkv_b,
                                           float* __restrict__ q) {
  int b = blockIdx.x;
  int j = threadIdx.x;
  __shared__ float xs[Cc];
  xs[j] = x[(size_t)b * Nn * Cc + j];
  __syncthreads();
  const float4* wr = (const float4*)(qkv_w + (size_t)j * Cc);
  const float4* xv = (const float4*)xs;
  float acc = qkv_b[j];
#pragma unroll 8
  for (int c4 = 0; c4 < Cc / 4; ++c4) {
    float4 w = wr[c4], xx = xv[c4];
    acc += w.x * xx.x + w.y * xx.y + w.z * xx.z + w.w * xx.w;
  }
  q[b * Cc + j] = acc;
}

// ---------------- B: r[b,h,c] = SCALE * sum_d q[b,h,d] * Wk[h,d,c] ------------
__global__ __launch_bounds__(768) void k_r(const float* __restrict__ q,
                                           const float* __restrict__ qkv_w,
                                           float* __restrict__ r) {
  int bh = blockIdx.x;
  int b = bh / Hh, h = bh % Hh;
  int c = threadIdx.x;
  __shared__ float qs[Dd];
  if (threadIdx.x < Dd) qs[threadIdx.x] = q[b * Cc + h * Dd + threadIdx.x];
  __syncthreads();
  float acc = 0.f;
#pragma unroll 8
  for (int d = 0; d < Dd; ++d)
    acc += qs[d] * qkv_w[(size_t)(Cc + h * Dd + d) * Cc + c];
  r[(size_t)bh * Cc + c] = acc * SCALE;
}

// -------- C: logits[b,h,n] = r[b,h,:] . x[b,n,:]  +  out[:,1:,:] = x[:,1:,:] --
#define TN 16
#define NT 37         // ceil(577/16)
#define XSLD 772      // padded row stride (772 % 32 == 4 -> 2-way max, free)
__global__ __launch_bounds__(192) void k_logits_copy(const float* __restrict__ x,
                                                     const float* __restrict__ r,
                                                     float* __restrict__ out,
                                                     float* __restrict__ logits) {
  int b = blockIdx.x / NT, tile = blockIdx.x % NT;
  int n0 = tile * TN;
  __shared__ float xs[TN * XSLD];
  const float4* x4 = (const float4*)(x + ((size_t)b * Nn + n0) * Cc);
  float4* o4 = (float4*)(out + ((size_t)b * Nn + n0) * Cc);
  for (int idx = threadIdx.x; idx < TN * (Cc / 4); idx += 192) {
    int i = idx / (Cc / 4), c4 = idx % (Cc / 4);
    int n = n0 + i;
    float4 v = make_float4(0.f, 0.f, 0.f, 0.f);
    if (n < Nn) v = x4[(size_t)i * (Cc / 4) + c4];
    *(float4*)&xs[i * XSLD + c4 * 4] = v;
    if (n >= 1 && n < Nn) o4[(size_t)i * (Cc / 4) + c4] = v;
  }
  __syncthreads();
  int h = threadIdx.x >> 4;   // 0..11
  int i = threadIdx.x & 15;   // 0..15
  const float4* r4 = (const float4*)(r + ((size_t)b * Hh + h) * Cc);
  const float4* xrow = (const float4*)&xs[i * XSLD];
  float acc = 0.f;
#pragma unroll 4
  for (int c4 = 0; c4 < Cc / 4; ++c4) {
    float4 rv = r4[c4], xv = xrow[c4];
    acc += rv.x * xv.x + rv.y * xv.y + rv.z * xv.z + rv.w * xv.w;
  }
  int n = n0 + i;
  if (n < Nn) logits[((size_t)b * Hh + h) * Nn + n] = acc;
}

// ---------------- D: softmax over n, write transposed attnT[b][n][h] ----------
__global__ __launch_bounds__(64) void k_softmax(const float* __restrict__ logits,
                                                float* __restrict__ attnT) {
  int bh = blockIdx.x;
  int b = bh / Hh, h = bh % Hh;
  const float* row = logits + (size_t)bh * Nn;
  int t = threadIdx.x;
  float vals[10];
  float m = -1e30f;
#pragma unroll
  for (int i = 0; i < 10; ++i) {
    int n = i * 64 + t;
    vals[i] = (n < Nn) ? row[n] : -1e30f;
    m = fmaxf(m, vals[i]);
  }
#pragma unroll
  for (int off = 32; off; off >>= 1) m = fmaxf(m, __shfl_down(m, off));
  m = __shfl(m, 0);
  float s = 0.f;
#pragma unroll
  for (int i = 0; i < 10; ++i) { vals[i] = __expf(vals[i] - m); s += vals[i]; }
#pragma unroll
  for (int off = 32; off; off >>= 1) s += __shfl_down(s, off);
  float inv = 1.f / __shfl(s, 0);
#pragma unroll
  for (int i = 0; i < 10; ++i) {
    int n = i * 64 + t;
    if (n < Nn) attnT[((size_t)b * Nn + n) * Hh + h] = vals[i] * inv;
  }
}

// ---------------- E: y[b,h,c] = sum_n attn[b,h,n] * x[b,n,c] ------------------
// attnT indices are block-uniform -> compiler scalarizes to s_load,
// FMA takes the SGPR operand directly (no LDS broadcast cost).
__global__ __launch_bounds__(256) void k_y(const float* __restrict__ x,
                                           const float* __restrict__ attnT,
                                           float* __restrict__ y) {
  int b = blockIdx.x / 3, chunk = blockIdx.x % 3;
  int c = chunk * 256 + threadIdx.x;
  float acc[Hh];
#pragma unroll
  for (int h = 0; h < Hh; ++h) acc[h] = 0.f;
  const float* xb = x + (size_t)b * Nn * Cc + c;
  const float* at = attnT + (size_t)b * Nn * Hh;
#pragma unroll 2
  for (int n = 0; n < Nn; ++n) {
    float xv = xb[(size_t)n * Cc];
#pragma unroll
    for (int h = 0; h < Hh; ++h) acc[h] += at[n * Hh + h] * xv;
  }
#pragma unroll
  for (int h = 0; h < Hh; ++h) y[((size_t)b * Hh + h) * Cc + c] = acc[h];
}

// ---------------- F: cls[b,j] = Wv[j,:] . y[b,h(j),:] + bv[j] -----------------
__global__ __launch_bounds__(768) void k_cls(const float* __restrict__ y,
                                             const float* __restrict__ qkv_w,
                                             const float* __restrict__ qkv_b,
                                             float* __restrict__ cls) {
  int b = blockIdx.x;
  int j = threadIdx.x;  // h*64 + d
  __shared__ float ys[Hh * Cc];
  for (int idx = j; idx < Hh * Cc; idx += 768) ys[idx] = y[(size_t)b * Hh * Cc + idx];
  __syncthreads();
  int h = j >> 6;
  const float4* wr = (const float4*)(qkv_w + (size_t)(2 * Cc + j) * Cc);
  const float4* yv = (const float4*)&ys[h * Cc];
  float acc = qkv_b[2 * Cc + j];
#pragma unroll 8
  for (int c4 = 0; c4 < Cc / 4; ++c4) {
    float4 w = wr[c4], yy = yv[c4];
    acc += w.x * yy.x + w.y * yy.y + w.z * yy.z + w.w * yy.w;
  }
  cls[b * Cc + j] = acc;
}

// ---------------- G: out[b,0,j] = proj_w[j,:] . cls[b,:] + proj_b[j] ----------
__global__ __launch_bounds__(768) void k_proj(const float* __restrict__ cls,
                                              const float* __restrict__ proj_w,
                                              const float* __restrict__ proj_b,
                                              float* __restrict__ out) {
  int b = blockIdx.x;
  int j = threadIdx.x;
  __shared__ float cs[Cc];
  cs[j] = cls[b * Cc + j];
  __syncthreads();
  const float4* wr = (const float4*)(proj_w + (size_t)j * Cc);
  const float4* cv = (const float4*)cs;
  float acc = proj_b[j];
#pragma unroll 8
  for (int c4 = 0; c4 < Cc / 4; ++c4) {
    float4 w = wr[c4], cc = cv[c4];
    acc += w.x * cc.x + w.y * cc.y + w.z * cc.z + w.w * cc.w;
  }
  out[(size_t)b * Nn * Cc + j] = acc;
}

extern "C" void kernel_launch(void* const* d_in, const int* in_sizes, int n_in,
                              void* d_out, int out_size, void* d_ws, size_t ws_size,
                              hipStream_t stream) {
  const float* x      = (const float*)d_in[0];
  const float* qkv_w  = (const float*)d_in[1];
  const float* qkv_b  = (const float*)d_in[2];
  const float* proj_w = (const float*)d_in[3];
  const float* proj_b = (const float*)d_in[4];
  float* out = (float*)d_out;
  float* ws = (float*)d_ws;

  float* q      = ws;
  float* r      = ws + 49152;
  float* logits = ws + 638976;
  float* attnT  = ws + 1082112;
  float* y      = ws + 1525248;
  float* cls    = ws + 2115072;

  k_q<<<Bz, 768, 0, stream>>>(x, qkv_w, qkv_b, q);
  k_r<<<Bz * Hh, 768, 0, stream>>>(q, qkv_w, r);
  k_logits_copy<<<Bz * NT, 192, 0, stream>>>(x, r, out, logits);
  k_softmax<<<Bz * Hh, 64, 0, stream>>>(logits, attnT);
  k_y<<<Bz * 3, 256, 0, stream>>>(x, attnT, y);
  k_cls<<<Bz, 768, 0, stream>>>(y, qkv_w, qkv_b, cls);
  k_proj<<<Bz, 768, 0, stream>>>(cls, proj_w, proj_b, out);
}

// Round 2
// 399.289 us; speedup vs baseline: 1.6190x; 1.6190x over previous
//
#include <hip/hip_runtime.h>

#define Bz 64
#define Nn 577
#define Cc 768
#define Hh 12
#define Dd 64
#define SCALE 0.125f

// ws layout (floats) — unchanged high-water vs round 1 (8.66 MB):
//   q:      0        .. 49152        [B][C]
//   r:      49152    .. 638976       [B][H][C]   (already * SCALE)
//   logits: 638976   .. 1082112      [B][H][N]
//   attnT:  1082112  .. 1525248      [B][N][H]
//   y:      1525248  .. 2115072      [B][H][C]   (zeroed, atomic-accumulated)
//   cls:    2115072  .. 2164224      [B][C]

// ---------------- A: q[b,j] = x[b,0,:] . qkv_w[j,:] + qkv_b[j] ----------------
// grid 64*6, block 128 (widened from 64 blocks -> all CUs active)
__global__ __launch_bounds__(128) void k_q(const float* __restrict__ x,
                                           const float* __restrict__ qkv_w,
                                           const float* __restrict__ qkv_b,
                                           float* __restrict__ q) {
  int b = blockIdx.x / 6, chunk = blockIdx.x % 6;
  int j = chunk * 128 + threadIdx.x;
  __shared__ float xs[Cc];
  for (int idx = threadIdx.x; idx < Cc; idx += 128)
    xs[idx] = x[(size_t)b * Nn * Cc + idx];
  __syncthreads();
  const float4* wr = (const float4*)(qkv_w + (size_t)j * Cc);
  const float4* xv = (const float4*)xs;
  float acc = qkv_b[j];
#pragma unroll 8
  for (int c4 = 0; c4 < Cc / 4; ++c4) {
    float4 w = wr[c4], xx = xv[c4];
    acc += w.x * xx.x + w.y * xx.y + w.z * xx.z + w.w * xx.w;
  }
  q[b * Cc + j] = acc;
}

// ---------------- B: r[b,h,c] = SCALE * sum_d q[b,h,d] * Wk[h,d,c] ------------
__global__ __launch_bounds__(768) void k_r(const float* __restrict__ q,
                                           const float* __restrict__ qkv_w,
                                           float* __restrict__ r) {
  int bh = blockIdx.x;
  int b = bh / Hh, h = bh % Hh;
  int c = threadIdx.x;
  __shared__ float qs[Dd];
  if (threadIdx.x < Dd) qs[threadIdx.x] = q[b * Cc + h * Dd + threadIdx.x];
  __syncthreads();
  float acc = 0.f;
#pragma unroll 8
  for (int d = 0; d < Dd; ++d)
    acc += qs[d] * qkv_w[(size_t)(Cc + h * Dd + d) * Cc + c];
  r[(size_t)bh * Cc + c] = acc * SCALE;
}

// -------- C: logits[b,h,n] = r[b,h,:] . x[b,n,:]  +  out[:,1:,:] = x[:,1:,:] --
// Register-resident r fragments (6 heads/wave), per-lane partial dot +
// shfl_xor butterfly. No LDS -> occupancy limited only by VGPRs.
// grid 64*73, block 256. wave pair (0,1)|(2,3) covers 4 n-rows x 12 heads.
#define LT 8
#define LNT 73  // ceil(577/8)
__global__ __launch_bounds__(256) void k_logits_copy(const float* __restrict__ x,
                                                     const float* __restrict__ r,
                                                     float* __restrict__ out,
                                                     float* __restrict__ logits) {
  int b = blockIdx.x / LNT, tile = blockIdx.x % LNT;
  int wave = threadIdx.x >> 6, lane = threadIdx.x & 63;
  int h0 = (wave & 1) * 6;
  int n0 = tile * LT + (wave >> 1) * 4;
  const float4* rbase = (const float4*)(r + ((size_t)b * Hh + h0) * Cc);
  float4 rf[6][3];
#pragma unroll
  for (int hh = 0; hh < 6; ++hh)
#pragma unroll
    for (int j = 0; j < 3; ++j)
      rf[hh][j] = rbase[hh * 192 + j * 64 + lane];
#pragma unroll
  for (int i = 0; i < 4; ++i) {
    int n = n0 + i;
    if (n < Nn) {
      const float4* xrow = (const float4*)(x + ((size_t)b * Nn + n) * Cc);
      float4 xv[3];
#pragma unroll
      for (int j = 0; j < 3; ++j) xv[j] = xrow[j * 64 + lane];
      if ((wave & 1) == 0 && n >= 1) {
        float4* orow = (float4*)(out + ((size_t)b * Nn + n) * Cc);
#pragma unroll
        for (int j = 0; j < 3; ++j) orow[j * 64 + lane] = xv[j];
      }
#pragma unroll
      for (int hh = 0; hh < 6; ++hh) {
        float p = 0.f;
#pragma unroll
        for (int j = 0; j < 3; ++j)
          p += rf[hh][j].x * xv[j].x + rf[hh][j].y * xv[j].y
             + rf[hh][j].z * xv[j].z + rf[hh][j].w * xv[j].w;
#pragma unroll
        for (int m = 1; m < 64; m <<= 1) p += __shfl_xor(p, m);
        if (lane == 0) logits[((size_t)b * Hh + h0 + hh) * Nn + n] = p;
      }
    }
  }
}

// ---------------- D: softmax over n, write transposed attnT[b][n][h] ----------
__global__ __launch_bounds__(64) void k_softmax(const float* __restrict__ logits,
                                                float* __restrict__ attnT) {
  int bh = blockIdx.x;
  int b = bh / Hh, h = bh % Hh;
  const float* row = logits + (size_t)bh * Nn;
  int t = threadIdx.x;
  float vals[10];
  float m = -1e30f;
#pragma unroll
  for (int i = 0; i < 10; ++i) {
    int n = i * 64 + t;
    vals[i] = (n < Nn) ? row[n] : -1e30f;
    m = fmaxf(m, vals[i]);
  }
#pragma unroll
  for (int off = 32; off; off >>= 1) m = fmaxf(m, __shfl_down(m, off));
  m = __shfl(m, 0);
  float s = 0.f;
#pragma unroll
  for (int i = 0; i < 10; ++i) { vals[i] = __expf(vals[i] - m); s += vals[i]; }
#pragma unroll
  for (int off = 32; off; off >>= 1) s += __shfl_down(s, off);
  float inv = 1.f / __shfl(s, 0);
#pragma unroll
  for (int i = 0; i < 10; ++i) {
    int n = i * 64 + t;
    if (n < Nn) attnT[((size_t)b * Nn + n) * Hh + h] = vals[i] * inv;
  }
}

// ---------------- zero y before atomic accumulation ---------------------------
__global__ __launch_bounds__(256) void k_zero(float* __restrict__ y) {
  ((float4*)y)[blockIdx.x * 256 + threadIdx.x] = make_float4(0.f, 0.f, 0.f, 0.f);
}

// ---------------- E: y[b,h,c] += sum_{n in seg} attn[b,h,n] * x[b,n,c] --------
// n split into 8 segments (512 blocks), float4 per thread, atomic accumulate.
#define YSEG 8
__global__ __launch_bounds__(192) void k_y(const float* __restrict__ x,
                                           const float* __restrict__ attnT,
                                           float* __restrict__ y) {
  int b = blockIdx.x / YSEG, seg = blockIdx.x % YSEG;
  int n0 = seg * Nn / YSEG, n1 = (seg + 1) * Nn / YSEG;
  int c4 = threadIdx.x;  // 0..191 float4 chunks = 768 floats
  float4 acc[Hh];
#pragma unroll
  for (int h = 0; h < Hh; ++h) acc[h] = make_float4(0.f, 0.f, 0.f, 0.f);
  const float4* x4 = (const float4*)(x + (size_t)b * Nn * Cc);
  const float* at = attnT + (size_t)b * Nn * Hh;
#pragma unroll 2
  for (int n = n0; n < n1; ++n) {
    float4 xv = x4[(size_t)n * 192 + c4];
#pragma unroll
    for (int h = 0; h < Hh; ++h) {
      float a = at[n * Hh + h];  // block-uniform -> s_load
      acc[h].x += a * xv.x; acc[h].y += a * xv.y;
      acc[h].z += a * xv.z; acc[h].w += a * xv.w;
    }
  }
  float* yb = y + (size_t)b * Hh * Cc;
#pragma unroll
  for (int h = 0; h < Hh; ++h) {
    float* p = yb + h * Cc + c4 * 4;
    atomicAdd(p + 0, acc[h].x); atomicAdd(p + 1, acc[h].y);
    atomicAdd(p + 2, acc[h].z); atomicAdd(p + 3, acc[h].w);
  }
}

// ---------------- F: cls[b,j] = Wv[j,:] . y[b,h(j),:] + bv[j] -----------------
// grid 64*6, block 128; stage only the 2 heads this chunk needs.
__global__ __launch_bounds__(128) void k_cls(const float* __restrict__ y,
                                             const float* __restrict__ qkv_w,
                                             const float* __restrict__ qkv_b,
                                             float* __restrict__ cls) {
  int b = blockIdx.x / 6, chunk = blockIdx.x % 6;
  int j = chunk * 128 + threadIdx.x;
  __shared__ float ys[2 * Cc];
  for (int idx = threadIdx.x; idx < 2 * Cc; idx += 128)
    ys[idx] = y[(size_t)b * Hh * Cc + (size_t)chunk * 2 * Cc + idx];
  __syncthreads();
  const float4* wr = (const float4*)(qkv_w + (size_t)(2 * Cc + j) * Cc);
  const float4* yv = (const float4*)&ys[((threadIdx.x >> 6) & 1) * Cc];
  float acc = qkv_b[2 * Cc + j];
#pragma unroll 8
  for (int c4 = 0; c4 < Cc / 4; ++c4) {
    float4 w = wr[c4], yy = yv[c4];
    acc += w.x * yy.x + w.y * yy.y + w.z * yy.z + w.w * yy.w;
  }
  cls[b * Cc + j] = acc;
}

// ---------------- G: out[b,0,j] = proj_w[j,:] . cls[b,:] + proj_b[j] ----------
__global__ __launch_bounds__(128) void k_proj(const float* __restrict__ cls,
                                              const float* __restrict__ proj_w,
                                              const float* __restrict__ proj_b,
                                              float* __restrict__ out) {
  int b = blockIdx.x / 6, chunk = blockIdx.x % 6;
  int j = chunk * 128 + threadIdx.x;
  __shared__ float cs[Cc];
  for (int idx = threadIdx.x; idx < Cc; idx += 128)
    cs[idx] = cls[b * Cc + idx];
  __syncthreads();
  const float4* wr = (const float4*)(proj_w + (size_t)j * Cc);
  const float4* cv = (const float4*)cs;
  float acc = proj_b[j];
#pragma unroll 8
  for (int c4 = 0; c4 < Cc / 4; ++c4) {
    float4 w = wr[c4], cc = cv[c4];
    acc += w.x * cc.x + w.y * cc.y + w.z * cc.z + w.w * cc.w;
  }
  out[(size_t)b * Nn * Cc + j] = acc;
}

extern "C" void kernel_launch(void* const* d_in, const int* in_sizes, int n_in,
                              void* d_out, int out_size, void* d_ws, size_t ws_size,
                              hipStream_t stream) {
  const float* x      = (const float*)d_in[0];
  const float* qkv_w  = (const float*)d_in[1];
  const float* qkv_b  = (const float*)d_in[2];
  const float* proj_w = (const float*)d_in[3];
  const float* proj_b = (const float*)d_in[4];
  float* out = (float*)d_out;
  float* ws = (float*)d_ws;

  float* q      = ws;
  float* r      = ws + 49152;
  float* logits = ws + 638976;
  float* attnT  = ws + 1082112;
  float* y      = ws + 1525248;
  float* cls    = ws + 2115072;

  k_zero<<<576, 256, 0, stream>>>(y);  // 589824 floats = 576*256 float4
  k_q<<<Bz * 6, 128, 0, stream>>>(x, qkv_w, qkv_b, q);
  k_r<<<Bz * Hh, 768, 0, stream>>>(q, qkv_w, r);
  k_logits_copy<<<Bz * LNT, 256, 0, stream>>>(x, r, out, logits);
  k_softmax<<<Bz * Hh, 64, 0, stream>>>(logits, attnT);
  k_y<<<Bz * YSEG, 192, 0, stream>>>(x, attnT, y);
  k_cls<<<Bz * 6, 128, 0, stream>>>(y, qkv_w, qkv_b, cls);
  k_proj<<<Bz * 6, 128, 0, stream>>>(cls, proj_w, proj_b, out);
}